// Round 15
// baseline (380.801 us; speedup 1.0000x reference)
//
#include <hip/hip_runtime.h>
#include <hip/hip_bf16.h>
#include <hip/hip_fp16.h>
#include <hip/hip_fp8.h>

// ---------------------------------------------------------------------------
// RewardGNN: 2-layer GCN (256->128->64) + mean-pool + linear head.
// Round 15: gathers are request-rate-limited (time constant across 512/256/128
//   byte rows). Pack 2 edges per wave-load: half-wave (32 lanes) per edge row
//   (fp8 row = 32 x u32; bf16 row = 32 x u32), cross-half __shfl_xor combine.
// xw1 fp8; h1 bf16; barrier-free gather2+pool fusion; one-u64-atomic CSR.
// ---------------------------------------------------------------------------

static inline int ceil_div_ll(long long a, int b) { return (int)((a + b - 1) / b); }

typedef __attribute__((ext_vector_type(8))) short bf16x8;
typedef __attribute__((ext_vector_type(4))) float f32x4;

#define FIX_SCALE 33554432.0f   // 2^25

__device__ inline unsigned short f2bf(float f) {
    __hip_bfloat16 h = __float2bfloat16(f);  // round-to-nearest-even
    return *reinterpret_cast<unsigned short*>(&h);
}
__device__ inline float bf2f(unsigned int u) {
    return __uint_as_float((u & 0xffffu) << 16);
}
__device__ inline unsigned char f32_to_fp8(float f) {
    return __hip_cvt_float_to_fp8(f, __HIP_SATFINITE, __HIP_E4M3);
}
// e4m3fn decode: bias 7; denormal = m * 2^-9
__device__ inline float fp8_to_f32(unsigned int v) {
    unsigned int s = v >> 7;
    unsigned int e = (v >> 3) & 15;
    unsigned int m = v & 7;
    float r;
    if (e) r = __uint_as_float(((e + 120) << 23) | (m << 20));
    else   r = (float)m * 0.001953125f;  // 2^-9
    return s ? -r : r;
}

// pk[i] = count<<32 | deg_fixed ; init deg=1.0 (self-loop), count=0
__global__ void k_init_pk(unsigned long long* __restrict__ pk, int n) {
    int i = blockIdx.x * blockDim.x + threadIdx.x;
    if (i < n) pk[i] = (unsigned long long)(1u << 25);
}

// 4 edges per thread: 4 independent u64 atomics in flight
__global__ void k_deg_count(const int* __restrict__ dst, const float* __restrict__ ew,
                            unsigned long long* __restrict__ pk, int* __restrict__ slot, int E) {
    int t = blockIdx.x * blockDim.x + threadIdx.x;
    int e = t * 4;
    if (e + 4 <= E) {
        int4   d4 = *(const int4*)(dst + e);
        float4 w4 = *(const float4*)(ew + e);
        unsigned long long o0 = atomicAdd(&pk[d4.x],
            (1ull << 32) | (unsigned long long)__float2uint_rn(w4.x * FIX_SCALE));
        unsigned long long o1 = atomicAdd(&pk[d4.y],
            (1ull << 32) | (unsigned long long)__float2uint_rn(w4.y * FIX_SCALE));
        unsigned long long o2 = atomicAdd(&pk[d4.z],
            (1ull << 32) | (unsigned long long)__float2uint_rn(w4.z * FIX_SCALE));
        unsigned long long o3 = atomicAdd(&pk[d4.w],
            (1ull << 32) | (unsigned long long)__float2uint_rn(w4.w * FIX_SCALE));
        *(int4*)(slot + e) = make_int4((int)(o0 >> 32), (int)(o1 >> 32),
                                       (int)(o2 >> 32), (int)(o3 >> 32));
    } else if (e < E) {
        for (int k = e; k < E; ++k) {
            unsigned int fx = __float2uint_rn(ew[k] * FIX_SCALE);
            unsigned long long old =
                atomicAdd(&pk[dst[k]], (1ull << 32) | (unsigned long long)fx);
            slot[k] = (int)(old >> 32);
        }
    }
}

// dinv[i] = rsqrt(deg), count[i] = in-count ; also zeroes sums (pool accum)
__global__ void k_finish(const unsigned long long* __restrict__ pk, float* __restrict__ dinv,
                         int* __restrict__ count, float* __restrict__ sums, int nsums, int n) {
    int i = blockIdx.x * blockDim.x + threadIdx.x;
    if (i < n) {
        unsigned long long v = pk[i];
        float deg = (float)(unsigned int)(v & 0xffffffffull) * (1.0f / FIX_SCALE);
        dinv[i] = (deg > 0.f) ? rsqrtf(deg) : 0.f;
        count[i] = (int)(v >> 32);
    }
    if (i < nsums) sums[i] = 0.0f;
}

// ------------------------- 3-phase parallel scan ---------------------------
constexpr int SC_T = 256;
constexpr int SC_PER = 16;
constexpr int SC_CHUNK = SC_T * SC_PER;

__global__ void k_scan_a(const int* __restrict__ count, int* __restrict__ bsum, int n) {
    __shared__ int lds[SC_T];
    int b = blockIdx.x, t = threadIdx.x;
    int base = b * SC_CHUNK + t * SC_PER;
    int s = 0;
#pragma unroll
    for (int k = 0; k < SC_PER; ++k) {
        int idx = base + k;
        if (idx < n) s += count[idx];
    }
    lds[t] = s;
    __syncthreads();
    for (int off = 128; off > 0; off >>= 1) {
        if (t < off) lds[t] += lds[t + off];
        __syncthreads();
    }
    if (t == 0) bsum[b] = lds[0];
}

__global__ void k_scan_b(int* __restrict__ bsum, int nb) {
    if (threadIdx.x == 0) {
        int run = 0;
        for (int i = 0; i < nb; ++i) { int c = bsum[i]; bsum[i] = run; run += c; }
    }
}

__global__ void k_scan_c(const int* __restrict__ count, int* __restrict__ rowptr,
                         const int* __restrict__ bsum, int n) {
    __shared__ int lds[SC_T];
    int b = blockIdx.x, t = threadIdx.x;
    int base = b * SC_CHUNK + t * SC_PER;
    int v[SC_PER];
    int s = 0;
#pragma unroll
    for (int k = 0; k < SC_PER; ++k) {
        int idx = base + k;
        v[k] = (idx < n) ? count[idx] : 0;
        s += v[k];
    }
    lds[t] = s;
    for (int off = 1; off < SC_T; off <<= 1) {
        __syncthreads();
        int tmp = (t >= off) ? lds[t - off] : 0;
        __syncthreads();
        lds[t] += tmp;
    }
    __syncthreads();
    int run = bsum[b] + lds[t] - s;
#pragma unroll
    for (int k = 0; k < SC_PER; ++k) {
        int idx = base + k;
        if (idx < n) {
            rowptr[idx] = run;
            run += v[k];
            if (idx == n - 1) rowptr[n] = run;
        }
    }
}

// Fill CSR without atomics: pos = rowptr[dst] + slot[e]; one int2 store.
__global__ void k_csr_fill(const int* __restrict__ src, const int* __restrict__ dst,
                           const float* __restrict__ ew, const float* __restrict__ dinv,
                           const int* __restrict__ rowptr, const int* __restrict__ slot,
                           int2* __restrict__ csr, int E) {
    int e = blockIdx.x * blockDim.x + threadIdx.x;
    if (e < E) {
        int s = src[e], d = dst[e];
        int pos = rowptr[d] + slot[e];
        float coef = dinv[s] * ew[e] * dinv[d];
        csr[pos] = make_int2(s, __float_as_int(coef));
    }
}

// ---------------------------------------------------------------------------
// W pre-pack into MFMA B-fragment layout (hi/lo bf16).
// ---------------------------------------------------------------------------
template <int KDIM, int ODIM>
__global__ void k_wpack(const float* __restrict__ W, unsigned short* __restrict__ wpk) {
    constexpr int NKS = KDIM / 32, NF = ODIM / 16;
    int t = blockIdx.x * blockDim.x + threadIdx.x;
    if (t >= NKS * NF * 64) return;
    int lane = t & 63;
    int nf   = (t >> 6) % NF;
    int ks   = t / (64 * NF);
    int col  = nf * 16 + (lane & 15);
    int kb   = ks * 32 + (lane >> 4) * 8;
    bf16x8 hi, lo;
#pragma unroll
    for (int i = 0; i < 8; ++i) {
        float w = W[(size_t)(kb + i) * ODIM + col];
        unsigned short h = f2bf(w);
        hi[i] = (short)h;
        lo[i] = (short)f2bf(w - bf2f(h));
    }
    size_t base = (size_t)t * 8;
    *(bf16x8*)(wpk + base) = hi;
    *(bf16x8*)(wpk + (size_t)KDIM * ODIM + base) = lo;
}

// ---------------------------------------------------------------------------
// GEMM1: f32 A, split-precision (3 mfma), FP8 e4m3 out.
// ---------------------------------------------------------------------------
template <int KDIM, int ODIM>
__global__ void k_gemm_mfma(const float* __restrict__ X,
                            const unsigned short* __restrict__ wpk,
                            unsigned char* __restrict__ Y, int n) {
    constexpr int NKS = KDIM / 32, NF = ODIM / 16;
    int wid  = threadIdx.x >> 6;
    int lane = threadIdx.x & 63;
    int rowbase = blockIdx.x * 64 + wid * 16;
    int arow = rowbase + (lane & 15);
    int kb0  = (lane >> 4) * 8;
    const unsigned short* wlo = wpk + (size_t)KDIM * ODIM;
    bool aok = (arow < n);
    const float* xr = X + (size_t)arow * KDIM + kb0;

    f32x4 acc[NF];
#pragma unroll
    for (int f = 0; f < NF; ++f) acc[f] = (f32x4){0.f, 0.f, 0.f, 0.f};

#pragma unroll
    for (int ks = 0; ks < NKS; ++ks) {
        f32x4 a0 = (f32x4){0.f, 0.f, 0.f, 0.f};
        f32x4 a1 = (f32x4){0.f, 0.f, 0.f, 0.f};
        if (aok) {
            a0 = *(const f32x4*)(xr + ks * 32);
            a1 = *(const f32x4*)(xr + ks * 32 + 4);
        }
        bf16x8 ahi, alo;
#pragma unroll
        for (int i = 0; i < 4; ++i) {
            unsigned short h0 = f2bf(a0[i]);
            ahi[i]     = (short)h0;
            alo[i]     = (short)f2bf(a0[i] - bf2f(h0));
            unsigned short h1 = f2bf(a1[i]);
            ahi[i + 4] = (short)h1;
            alo[i + 4] = (short)f2bf(a1[i] - bf2f(h1));
        }
#pragma unroll
        for (int f = 0; f < NF; ++f) {
            size_t fb = (((size_t)ks * NF + f) * 64 + lane) * 8;
            bf16x8 bhi = *(const bf16x8*)(wpk + fb);
            bf16x8 blo = *(const bf16x8*)(wlo + fb);
            acc[f] = __builtin_amdgcn_mfma_f32_16x16x32_bf16(ahi, bhi, acc[f], 0, 0, 0);
            acc[f] = __builtin_amdgcn_mfma_f32_16x16x32_bf16(alo, bhi, acc[f], 0, 0, 0);
            acc[f] = __builtin_amdgcn_mfma_f32_16x16x32_bf16(ahi, blo, acc[f], 0, 0, 0);
        }
    }

    int r0  = rowbase + (lane >> 4) * 4;
    int col = lane & 15;
#pragma unroll
    for (int f = 0; f < NF; ++f) {
#pragma unroll
        for (int i = 0; i < 4; ++i) {
            int r = r0 + i;
            if (r < n) Y[(size_t)r * ODIM + f * 16 + col] = f32_to_fp8(acc[f][i]);
        }
    }
}

// ---------------------------------------------------------------------------
// GEMM2: bf16 A (h1 stored bf16 -> exact fragment, no split), B hi/lo (2 mfma).
// ---------------------------------------------------------------------------
template <int KDIM, int ODIM>
__global__ void k_gemm_mfma_bfA(const unsigned short* __restrict__ X,
                                const unsigned short* __restrict__ wpk,
                                unsigned short* __restrict__ Y, int n) {
    constexpr int NKS = KDIM / 32, NF = ODIM / 16;
    int wid  = threadIdx.x >> 6;
    int lane = threadIdx.x & 63;
    int rowbase = blockIdx.x * 64 + wid * 16;
    int arow = rowbase + (lane & 15);
    int kb0  = (lane >> 4) * 8;
    const unsigned short* wlo = wpk + (size_t)KDIM * ODIM;
    bool aok = (arow < n);
    const unsigned short* xr = X + (size_t)arow * KDIM + kb0;

    f32x4 acc[NF];
#pragma unroll
    for (int f = 0; f < NF; ++f) acc[f] = (f32x4){0.f, 0.f, 0.f, 0.f};

#pragma unroll
    for (int ks = 0; ks < NKS; ++ks) {
        bf16x8 a = (bf16x8){0, 0, 0, 0, 0, 0, 0, 0};
        if (aok) a = *(const bf16x8*)(xr + ks * 32);
#pragma unroll
        for (int f = 0; f < NF; ++f) {
            size_t fb = (((size_t)ks * NF + f) * 64 + lane) * 8;
            bf16x8 bhi = *(const bf16x8*)(wpk + fb);
            bf16x8 blo = *(const bf16x8*)(wlo + fb);
            acc[f] = __builtin_amdgcn_mfma_f32_16x16x32_bf16(a, bhi, acc[f], 0, 0, 0);
            acc[f] = __builtin_amdgcn_mfma_f32_16x16x32_bf16(a, blo, acc[f], 0, 0, 0);
        }
    }

    int r0  = rowbase + (lane >> 4) * 4;
    int col = lane & 15;
#pragma unroll
    for (int f = 0; f < NF; ++f) {
#pragma unroll
        for (int i = 0; i < 4; ++i) {
            int r = r0 + i;
            if (r < n) Y[(size_t)r * ODIM + f * 16 + col] = f2bf(acc[f][i]);
        }
    }
}

// ---------------------------------------------------------------------------
// Gather1 (fp8 in, bf16 out), 2 EDGES PER WAVE-LOAD:
//   half = lane>>5 picks edge e+2k+half; lane hl=lane&31 covers features
//   4hl..4hl+3 via one u32 (4 fp8). Cross-half combine via __shfl_xor(.,32).
// ---------------------------------------------------------------------------
__global__ __launch_bounds__(256, 2)
void k_gather1(const unsigned char* __restrict__ xw, const int* __restrict__ rowptr,
               const int2* __restrict__ csr,
               const float* __restrict__ dinv, const float* __restrict__ bias,
               unsigned short* __restrict__ out, int n) {
    int wave = threadIdx.x >> 6;
    int lane = threadIdx.x & 63;
    int half = lane >> 5;
    int hl   = lane & 31;
    int i = blockIdx.x * 4 + wave;
    if (i >= n) return;

    float dv = dinv[i];
    float sl = dv * dv;
    int e0 = __builtin_amdgcn_readfirstlane(rowptr[i]);
    int e1 = __builtin_amdgcn_readfirstlane(rowptr[i + 1]);

    // self-loop (features 4hl..4hl+3, redundant across halves)
    unsigned int su = *(const unsigned int*)(xw + (size_t)i * 128 + hl * 4);
    float s0 = fp8_to_f32(su & 0xff) * sl;
    float s1 = fp8_to_f32((su >> 8) & 0xff) * sl;
    float s2 = fp8_to_f32((su >> 16) & 0xff) * sl;
    float s3 = fp8_to_f32(su >> 24) * sl;

    float ac0 = 0.f, ac1 = 0.f, ac2 = 0.f, ac3 = 0.f;
    int e = e0;
    for (; e + 8 <= e1; e += 8) {
        int2 q0 = csr[e + 0 + half];
        int2 q1 = csr[e + 2 + half];
        int2 q2 = csr[e + 4 + half];
        int2 q3 = csr[e + 6 + half];
        unsigned int u0 = *(const unsigned int*)(xw + (size_t)q0.x * 128 + hl * 4);
        unsigned int u1 = *(const unsigned int*)(xw + (size_t)q1.x * 128 + hl * 4);
        unsigned int u2 = *(const unsigned int*)(xw + (size_t)q2.x * 128 + hl * 4);
        unsigned int u3 = *(const unsigned int*)(xw + (size_t)q3.x * 128 + hl * 4);
        float c0 = __int_as_float(q0.y), c1 = __int_as_float(q1.y);
        float c2 = __int_as_float(q2.y), c3 = __int_as_float(q3.y);
        ac0 += c0 * fp8_to_f32(u0 & 0xff);         ac1 += c0 * fp8_to_f32((u0 >> 8) & 0xff);
        ac2 += c0 * fp8_to_f32((u0 >> 16) & 0xff); ac3 += c0 * fp8_to_f32(u0 >> 24);
        ac0 += c1 * fp8_to_f32(u1 & 0xff);         ac1 += c1 * fp8_to_f32((u1 >> 8) & 0xff);
        ac2 += c1 * fp8_to_f32((u1 >> 16) & 0xff); ac3 += c1 * fp8_to_f32(u1 >> 24);
        ac0 += c2 * fp8_to_f32(u2 & 0xff);         ac1 += c2 * fp8_to_f32((u2 >> 8) & 0xff);
        ac2 += c2 * fp8_to_f32((u2 >> 16) & 0xff); ac3 += c2 * fp8_to_f32(u2 >> 24);
        ac0 += c3 * fp8_to_f32(u3 & 0xff);         ac1 += c3 * fp8_to_f32((u3 >> 8) & 0xff);
        ac2 += c3 * fp8_to_f32((u3 >> 16) & 0xff); ac3 += c3 * fp8_to_f32(u3 >> 24);
    }
    for (; e + 2 <= e1; e += 2) {
        int2 q = csr[e + half];
        unsigned int u = *(const unsigned int*)(xw + (size_t)q.x * 128 + hl * 4);
        float c = __int_as_float(q.y);
        ac0 += c * fp8_to_f32(u & 0xff);         ac1 += c * fp8_to_f32((u >> 8) & 0xff);
        ac2 += c * fp8_to_f32((u >> 16) & 0xff); ac3 += c * fp8_to_f32(u >> 24);
    }
    if (e < e1) {  // single edge: mask half 1
        int2 q = csr[e];
        unsigned int u = *(const unsigned int*)(xw + (size_t)q.x * 128 + hl * 4);
        float c = half ? 0.f : __int_as_float(q.y);
        ac0 += c * fp8_to_f32(u & 0xff);         ac1 += c * fp8_to_f32((u >> 8) & 0xff);
        ac2 += c * fp8_to_f32((u >> 16) & 0xff); ac3 += c * fp8_to_f32(u >> 24);
    }
    // cross-half combine
    ac0 += __shfl_xor(ac0, 32);
    ac1 += __shfl_xor(ac1, 32);
    ac2 += __shfl_xor(ac2, 32);
    ac3 += __shfl_xor(ac3, 32);
    float4 bb = ((const float4*)bias)[hl];
    float f0 = fmaxf(ac0 + s0 + bb.x, 0.f);
    float f1 = fmaxf(ac1 + s1 + bb.y, 0.f);
    float f2 = fmaxf(ac2 + s2 + bb.z, 0.f);
    float f3 = fmaxf(ac3 + s3 + bb.w, 0.f);
    // write: half0 -> u32[2hl] = (f0,f1) ; half1 -> u32[2hl+1] = (f2,f3)
    unsigned int w = half ? ((unsigned int)f2bf(f2) | ((unsigned int)f2bf(f3) << 16))
                          : ((unsigned int)f2bf(f0) | ((unsigned int)f2bf(f1) << 16));
    ((unsigned int*)(out + (size_t)i * 128))[2 * hl + half] = w;
}

// ---------------------------------------------------------------------------
// Gather2+pool (bf16 in), 2 EDGES PER WAVE-LOAD, barrier-free, NPW=4 nodes
// per wave sequential; pooled row in registers; per-graph-run atomics.
// Lane hl covers features 2hl, 2hl+1 via one u32 (2 bf16).
// ---------------------------------------------------------------------------
__global__ __launch_bounds__(256, 2)
void k_gather2_pool(const unsigned short* __restrict__ xw, const int* __restrict__ rowptr,
                    const int2* __restrict__ csr,
                    const float* __restrict__ dinv, const float* __restrict__ bias,
                    const int* __restrict__ batch, float* __restrict__ sums, int n) {
    constexpr int NPW = 4;
    int gwave = (blockIdx.x * blockDim.x + threadIdx.x) >> 6;
    int lane = threadIdx.x & 63;
    int half = lane >> 5;
    int hl   = lane & 31;
    int i0 = gwave * NPW;
    if (i0 >= n) return;
    int i1 = min(i0 + NPW, n);

    float2 bb = ((const float2*)bias)[hl];  // features 2hl, 2hl+1
    float p0 = 0.f, p1 = 0.f;
    int cg = __builtin_amdgcn_readfirstlane(batch[i0]);

    for (int i = i0; i < i1; ++i) {
        int g = __builtin_amdgcn_readfirstlane(batch[i]);
        if (g != cg) {
            float pv = half ? p1 : p0;
            atomicAdd(&sums[cg * 64 + 2 * hl + half], pv);
            p0 = 0.f; p1 = 0.f;
            cg = g;
        }
        float dv = dinv[i];
        float sl = dv * dv;
        int e0 = __builtin_amdgcn_readfirstlane(rowptr[i]);
        int e1 = __builtin_amdgcn_readfirstlane(rowptr[i + 1]);

        unsigned int su = ((const unsigned int*)(xw + (size_t)i * 64))[hl];
        float s0 = bf2f(su) * sl;
        float s1 = bf2f(su >> 16) * sl;
        float a0 = 0.f, a1 = 0.f;
        int e = e0;
        for (; e + 8 <= e1; e += 8) {
            int2 q0 = csr[e + 0 + half];
            int2 q1 = csr[e + 2 + half];
            int2 q2 = csr[e + 4 + half];
            int2 q3 = csr[e + 6 + half];
            unsigned int u0 = ((const unsigned int*)(xw + (size_t)q0.x * 64))[hl];
            unsigned int u1 = ((const unsigned int*)(xw + (size_t)q1.x * 64))[hl];
            unsigned int u2 = ((const unsigned int*)(xw + (size_t)q2.x * 64))[hl];
            unsigned int u3 = ((const unsigned int*)(xw + (size_t)q3.x * 64))[hl];
            float c0 = __int_as_float(q0.y), c1 = __int_as_float(q1.y);
            float c2 = __int_as_float(q2.y), c3 = __int_as_float(q3.y);
            a0 += c0 * bf2f(u0); a1 += c0 * bf2f(u0 >> 16);
            a0 += c1 * bf2f(u1); a1 += c1 * bf2f(u1 >> 16);
            a0 += c2 * bf2f(u2); a1 += c2 * bf2f(u2 >> 16);
            a0 += c3 * bf2f(u3); a1 += c3 * bf2f(u3 >> 16);
        }
        for (; e + 2 <= e1; e += 2) {
            int2 q = csr[e + half];
            unsigned int u = ((const unsigned int*)(xw + (size_t)q.x * 64))[hl];
            float c = __int_as_float(q.y);
            a0 += c * bf2f(u); a1 += c * bf2f(u >> 16);
        }
        if (e < e1) {  // single edge: mask half 1
            int2 q = csr[e];
            unsigned int u = ((const unsigned int*)(xw + (size_t)q.x * 64))[hl];
            float c = half ? 0.f : __int_as_float(q.y);
            a0 += c * bf2f(u); a1 += c * bf2f(u >> 16);
        }
        a0 += __shfl_xor(a0, 32);
        a1 += __shfl_xor(a1, 32);
        p0 += fmaxf(a0 + s0 + bb.x, 0.f);
        p1 += fmaxf(a1 + s1 + bb.y, 0.f);
    }
    float pv = half ? p1 : p0;
    atomicAdd(&sums[cg * 64 + 2 * hl + half], pv);
}

// out[g] = dot(sums[g]/cnt, Wfc) + bfc ; cnt via binary search on sorted batch
__global__ void k_head(const float* __restrict__ sums, const int* __restrict__ batch,
                       const float* __restrict__ Wfc, const float* __restrict__ bfc,
                       float* __restrict__ out, int n) {
    int g = blockIdx.x;
    int f = threadIdx.x;  // 64 threads = 1 wave
    int lo0 = 0, hi0 = n;
    while (lo0 < hi0) { int m = (lo0 + hi0) >> 1; if (batch[m] < g) lo0 = m + 1; else hi0 = m; }
    int lo1 = lo0, hi1 = n;
    while (lo1 < hi1) { int m = (lo1 + hi1) >> 1; if (batch[m] < g + 1) lo1 = m + 1; else hi1 = m; }
    float cnt = (float)(lo1 - lo0);
    float v = sums[g * 64 + f] * Wfc[f];
#pragma unroll
    for (int o = 32; o > 0; o >>= 1) v += __shfl_down(v, o);
    if (f == 0) out[g] = v / fmaxf(cnt, 1.0f) + bfc[0];
}

extern "C" void kernel_launch(void* const* d_in, const int* in_sizes, int n_in,
                              void* d_out, int out_size, void* d_ws, size_t ws_size,
                              hipStream_t stream) {
    const float* x    = (const float*)d_in[0];
    const int*   ei   = (const int*)d_in[1];
    const float* ew   = (const float*)d_in[2];
    const int*   bat  = (const int*)d_in[3];
    const float* W1   = (const float*)d_in[4];
    const float* b1   = (const float*)d_in[5];
    const float* W2   = (const float*)d_in[6];
    const float* b2   = (const float*)d_in[7];
    const float* Wfc  = (const float*)d_in[8];
    const float* bfc  = (const float*)d_in[9];
    float*       out  = (float*)d_out;

    const int N = in_sizes[0] / 256;
    const int E = in_sizes[2];
    const int G = out_size;

    const int* src = ei;
    const int* dst = ei + E;

    const int NB_SCAN = (N + SC_CHUNK - 1) / SC_CHUNK;

    // workspace layout (8B-aligned chunks)
    const int Npad = (N + 4) & ~3;
    unsigned long long* pk     = (unsigned long long*)d_ws;          // N u64
    float*              dinv   = (float*)(pk + Npad);                // N
    int*                count  = (int*)(dinv + Npad);                // N
    int*                rowptr = count + Npad;                       // N+1
    int*                bsum   = rowptr + Npad;                      // NB_SCAN
    int*                slot   = bsum + ((NB_SCAN + 4) & ~3);        // E
    int2*               csr    = (int2*)(slot + ((E + 4) & ~3));    // E int2
    unsigned short*     wpk1   = (unsigned short*)(csr + E);        // 2*256*128
    unsigned short*     wpk2   = wpk1 + 2 * 256 * 128;               // 2*128*64
    float*              sums   = (float*)(wpk2 + 2 * 128 * 64);     // G*64
    unsigned char*      bufA   = (unsigned char*)(sums + ((G * 64 + 4) & ~3)); // N*128 B: xw1 fp8 / xw2 bf16
    unsigned short*     bufH1  = (unsigned short*)(bufA + (size_t)N * 128);    // N*128 bf16: h1

    const int B = 256;

    // 1) packed degree + count (+ per-edge slot); finish also zeroes sums
    k_init_pk<<<ceil_div_ll(N, B), B, 0, stream>>>(pk, N);
    k_deg_count<<<ceil_div_ll((E + 3) / 4, B), B, 0, stream>>>(dst, ew, pk, slot, E);
    k_finish<<<ceil_div_ll(N, B), B, 0, stream>>>(pk, dinv, count, sums, G * 64, N);

    // 2) CSR build: parallel scan + atomic-free fill
    k_scan_a<<<NB_SCAN, SC_T, 0, stream>>>(count, bsum, N);
    k_scan_b<<<1, 64, 0, stream>>>(bsum, NB_SCAN);
    k_scan_c<<<NB_SCAN, SC_T, 0, stream>>>(count, rowptr, bsum, N);
    k_csr_fill<<<ceil_div_ll(E, B), B, 0, stream>>>(src, dst, ew, dinv, rowptr,
                                                    slot, csr, E);

    // W pre-pack
    k_wpack<256, 128><<<(8 * 8 * 64 + B - 1) / B, B, 0, stream>>>(W1, wpk1);
    k_wpack<128, 64><<<(4 * 4 * 64 + B - 1) / B, B, 0, stream>>>(W2, wpk2);

    // 3) layer 1: xw1(fp8) = x @ W1 ; h1(bf16) = relu(gather + b1)
    k_gemm_mfma<256, 128><<<ceil_div_ll(N, 64), 256, 0, stream>>>(x, wpk1, bufA, N);
    k_gather1<<<ceil_div_ll(N, 4), 256, 0, stream>>>(
        bufA, rowptr, csr, dinv, b1, bufH1, N);

    // 4) layer 2: xw2(bf16) = h1(bf16) @ W2 ; gather fused with mean-pool
    k_gemm_mfma_bfA<128, 64><<<ceil_div_ll(N, 64), 256, 0, stream>>>(
        bufH1, wpk2, (unsigned short*)bufA, N);
    {
        int waves = ceil_div_ll(N, 4);           // one wave per 4 nodes
        int blocks = ceil_div_ll(waves, 4);      // 4 waves per block
        k_gather2_pool<<<blocks, 256, 0, stream>>>(
            (const unsigned short*)bufA, rowptr, csr, dinv, b2, bat, sums, N);
    }

    // 5) head
    k_head<<<G, 64, 0, stream>>>(sums, bat, Wfc, bfc, out, N);
}

// Round 16
// 353.431 us; speedup vs baseline: 1.0774x; 1.0774x over previous
//
#include <hip/hip_runtime.h>
#include <hip/hip_bf16.h>
#include <hip/hip_fp16.h>
#include <hip/hip_fp8.h>

// ---------------------------------------------------------------------------
// RewardGNN: 2-layer GCN (256->128->64) + mean-pool + linear head.
// Round 16: round 15's half-wave gather1 became VALU-bound (90%) on SOFTWARE
//   fp8 decode. Swap to hardware v_cvt_pk_f32_fp8 (2 bytes -> 2 f32 / instr).
// Structure otherwise identical to round 15.
// ---------------------------------------------------------------------------

static inline int ceil_div_ll(long long a, int b) { return (int)((a + b - 1) / b); }

typedef __attribute__((ext_vector_type(8))) short bf16x8;
typedef __attribute__((ext_vector_type(4))) float f32x4;
typedef __attribute__((ext_vector_type(2))) float vf2;

#define FIX_SCALE 33554432.0f   // 2^25

__device__ inline unsigned short f2bf(float f) {
    __hip_bfloat16 h = __float2bfloat16(f);  // round-to-nearest-even
    return *reinterpret_cast<unsigned short*>(&h);
}
__device__ inline float bf2f(unsigned int u) {
    return __uint_as_float((u & 0xffffu) << 16);
}
__device__ inline unsigned char f32_to_fp8(float f) {
    return __hip_cvt_float_to_fp8(f, __HIP_SATFINITE, __HIP_E4M3);
}

// pk[i] = count<<32 | deg_fixed ; init deg=1.0 (self-loop), count=0
__global__ void k_init_pk(unsigned long long* __restrict__ pk, int n) {
    int i = blockIdx.x * blockDim.x + threadIdx.x;
    if (i < n) pk[i] = (unsigned long long)(1u << 25);
}

// 4 edges per thread: 4 independent u64 atomics in flight
__global__ void k_deg_count(const int* __restrict__ dst, const float* __restrict__ ew,
                            unsigned long long* __restrict__ pk, int* __restrict__ slot, int E) {
    int t = blockIdx.x * blockDim.x + threadIdx.x;
    int e = t * 4;
    if (e + 4 <= E) {
        int4   d4 = *(const int4*)(dst + e);
        float4 w4 = *(const float4*)(ew + e);
        unsigned long long o0 = atomicAdd(&pk[d4.x],
            (1ull << 32) | (unsigned long long)__float2uint_rn(w4.x * FIX_SCALE));
        unsigned long long o1 = atomicAdd(&pk[d4.y],
            (1ull << 32) | (unsigned long long)__float2uint_rn(w4.y * FIX_SCALE));
        unsigned long long o2 = atomicAdd(&pk[d4.z],
            (1ull << 32) | (unsigned long long)__float2uint_rn(w4.z * FIX_SCALE));
        unsigned long long o3 = atomicAdd(&pk[d4.w],
            (1ull << 32) | (unsigned long long)__float2uint_rn(w4.w * FIX_SCALE));
        *(int4*)(slot + e) = make_int4((int)(o0 >> 32), (int)(o1 >> 32),
                                       (int)(o2 >> 32), (int)(o3 >> 32));
    } else if (e < E) {
        for (int k = e; k < E; ++k) {
            unsigned int fx = __float2uint_rn(ew[k] * FIX_SCALE);
            unsigned long long old =
                atomicAdd(&pk[dst[k]], (1ull << 32) | (unsigned long long)fx);
            slot[k] = (int)(old >> 32);
        }
    }
}

// dinv[i] = rsqrt(deg), count[i] = in-count ; also zeroes sums (pool accum)
__global__ void k_finish(const unsigned long long* __restrict__ pk, float* __restrict__ dinv,
                         int* __restrict__ count, float* __restrict__ sums, int nsums, int n) {
    int i = blockIdx.x * blockDim.x + threadIdx.x;
    if (i < n) {
        unsigned long long v = pk[i];
        float deg = (float)(unsigned int)(v & 0xffffffffull) * (1.0f / FIX_SCALE);
        dinv[i] = (deg > 0.f) ? rsqrtf(deg) : 0.f;
        count[i] = (int)(v >> 32);
    }
    if (i < nsums) sums[i] = 0.0f;
}

// ------------------------- 3-phase parallel scan ---------------------------
constexpr int SC_T = 256;
constexpr int SC_PER = 16;
constexpr int SC_CHUNK = SC_T * SC_PER;

__global__ void k_scan_a(const int* __restrict__ count, int* __restrict__ bsum, int n) {
    __shared__ int lds[SC_T];
    int b = blockIdx.x, t = threadIdx.x;
    int base = b * SC_CHUNK + t * SC_PER;
    int s = 0;
#pragma unroll
    for (int k = 0; k < SC_PER; ++k) {
        int idx = base + k;
        if (idx < n) s += count[idx];
    }
    lds[t] = s;
    __syncthreads();
    for (int off = 128; off > 0; off >>= 1) {
        if (t < off) lds[t] += lds[t + off];
        __syncthreads();
    }
    if (t == 0) bsum[b] = lds[0];
}

__global__ void k_scan_b(int* __restrict__ bsum, int nb) {
    if (threadIdx.x == 0) {
        int run = 0;
        for (int i = 0; i < nb; ++i) { int c = bsum[i]; bsum[i] = run; run += c; }
    }
}

__global__ void k_scan_c(const int* __restrict__ count, int* __restrict__ rowptr,
                         const int* __restrict__ bsum, int n) {
    __shared__ int lds[SC_T];
    int b = blockIdx.x, t = threadIdx.x;
    int base = b * SC_CHUNK + t * SC_PER;
    int v[SC_PER];
    int s = 0;
#pragma unroll
    for (int k = 0; k < SC_PER; ++k) {
        int idx = base + k;
        v[k] = (idx < n) ? count[idx] : 0;
        s += v[k];
    }
    lds[t] = s;
    for (int off = 1; off < SC_T; off <<= 1) {
        __syncthreads();
        int tmp = (t >= off) ? lds[t - off] : 0;
        __syncthreads();
        lds[t] += tmp;
    }
    __syncthreads();
    int run = bsum[b] + lds[t] - s;
#pragma unroll
    for (int k = 0; k < SC_PER; ++k) {
        int idx = base + k;
        if (idx < n) {
            rowptr[idx] = run;
            run += v[k];
            if (idx == n - 1) rowptr[n] = run;
        }
    }
}

// Fill CSR without atomics: pos = rowptr[dst] + slot[e]; one int2 store.
__global__ void k_csr_fill(const int* __restrict__ src, const int* __restrict__ dst,
                           const float* __restrict__ ew, const float* __restrict__ dinv,
                           const int* __restrict__ rowptr, const int* __restrict__ slot,
                           int2* __restrict__ csr, int E) {
    int e = blockIdx.x * blockDim.x + threadIdx.x;
    if (e < E) {
        int s = src[e], d = dst[e];
        int pos = rowptr[d] + slot[e];
        float coef = dinv[s] * ew[e] * dinv[d];
        csr[pos] = make_int2(s, __float_as_int(coef));
    }
}

// ---------------------------------------------------------------------------
// W pre-pack into MFMA B-fragment layout (hi/lo bf16).
// ---------------------------------------------------------------------------
template <int KDIM, int ODIM>
__global__ void k_wpack(const float* __restrict__ W, unsigned short* __restrict__ wpk) {
    constexpr int NKS = KDIM / 32, NF = ODIM / 16;
    int t = blockIdx.x * blockDim.x + threadIdx.x;
    if (t >= NKS * NF * 64) return;
    int lane = t & 63;
    int nf   = (t >> 6) % NF;
    int ks   = t / (64 * NF);
    int col  = nf * 16 + (lane & 15);
    int kb   = ks * 32 + (lane >> 4) * 8;
    bf16x8 hi, lo;
#pragma unroll
    for (int i = 0; i < 8; ++i) {
        float w = W[(size_t)(kb + i) * ODIM + col];
        unsigned short h = f2bf(w);
        hi[i] = (short)h;
        lo[i] = (short)f2bf(w - bf2f(h));
    }
    size_t base = (size_t)t * 8;
    *(bf16x8*)(wpk + base) = hi;
    *(bf16x8*)(wpk + (size_t)KDIM * ODIM + base) = lo;
}

// ---------------------------------------------------------------------------
// GEMM1: f32 A, split-precision (3 mfma), FP8 e4m3 out.
// ---------------------------------------------------------------------------
template <int KDIM, int ODIM>
__global__ void k_gemm_mfma(const float* __restrict__ X,
                            const unsigned short* __restrict__ wpk,
                            unsigned char* __restrict__ Y, int n) {
    constexpr int NKS = KDIM / 32, NF = ODIM / 16;
    int wid  = threadIdx.x >> 6;
    int lane = threadIdx.x & 63;
    int rowbase = blockIdx.x * 64 + wid * 16;
    int arow = rowbase + (lane & 15);
    int kb0  = (lane >> 4) * 8;
    const unsigned short* wlo = wpk + (size_t)KDIM * ODIM;
    bool aok = (arow < n);
    const float* xr = X + (size_t)arow * KDIM + kb0;

    f32x4 acc[NF];
#pragma unroll
    for (int f = 0; f < NF; ++f) acc[f] = (f32x4){0.f, 0.f, 0.f, 0.f};

#pragma unroll
    for (int ks = 0; ks < NKS; ++ks) {
        f32x4 a0 = (f32x4){0.f, 0.f, 0.f, 0.f};
        f32x4 a1 = (f32x4){0.f, 0.f, 0.f, 0.f};
        if (aok) {
            a0 = *(const f32x4*)(xr + ks * 32);
            a1 = *(const f32x4*)(xr + ks * 32 + 4);
        }
        bf16x8 ahi, alo;
#pragma unroll
        for (int i = 0; i < 4; ++i) {
            unsigned short h0 = f2bf(a0[i]);
            ahi[i]     = (short)h0;
            alo[i]     = (short)f2bf(a0[i] - bf2f(h0));
            unsigned short h1 = f2bf(a1[i]);
            ahi[i + 4] = (short)h1;
            alo[i + 4] = (short)f2bf(a1[i] - bf2f(h1));
        }
#pragma unroll
        for (int f = 0; f < NF; ++f) {
            size_t fb = (((size_t)ks * NF + f) * 64 + lane) * 8;
            bf16x8 bhi = *(const bf16x8*)(wpk + fb);
            bf16x8 blo = *(const bf16x8*)(wlo + fb);
            acc[f] = __builtin_amdgcn_mfma_f32_16x16x32_bf16(ahi, bhi, acc[f], 0, 0, 0);
            acc[f] = __builtin_amdgcn_mfma_f32_16x16x32_bf16(alo, bhi, acc[f], 0, 0, 0);
            acc[f] = __builtin_amdgcn_mfma_f32_16x16x32_bf16(ahi, blo, acc[f], 0, 0, 0);
        }
    }

    int r0  = rowbase + (lane >> 4) * 4;
    int col = lane & 15;
#pragma unroll
    for (int f = 0; f < NF; ++f) {
#pragma unroll
        for (int i = 0; i < 4; ++i) {
            int r = r0 + i;
            if (r < n) Y[(size_t)r * ODIM + f * 16 + col] = f32_to_fp8(acc[f][i]);
        }
    }
}

// ---------------------------------------------------------------------------
// GEMM2: bf16 A (h1 stored bf16 -> exact fragment, no split), B hi/lo (2 mfma).
// ---------------------------------------------------------------------------
template <int KDIM, int ODIM>
__global__ void k_gemm_mfma_bfA(const unsigned short* __restrict__ X,
                                const unsigned short* __restrict__ wpk,
                                unsigned short* __restrict__ Y, int n) {
    constexpr int NKS = KDIM / 32, NF = ODIM / 16;
    int wid  = threadIdx.x >> 6;
    int lane = threadIdx.x & 63;
    int rowbase = blockIdx.x * 64 + wid * 16;
    int arow = rowbase + (lane & 15);
    int kb0  = (lane >> 4) * 8;
    const unsigned short* wlo = wpk + (size_t)KDIM * ODIM;
    bool aok = (arow < n);
    const unsigned short* xr = X + (size_t)arow * KDIM + kb0;

    f32x4 acc[NF];
#pragma unroll
    for (int f = 0; f < NF; ++f) acc[f] = (f32x4){0.f, 0.f, 0.f, 0.f};

#pragma unroll
    for (int ks = 0; ks < NKS; ++ks) {
        bf16x8 a = (bf16x8){0, 0, 0, 0, 0, 0, 0, 0};
        if (aok) a = *(const bf16x8*)(xr + ks * 32);
#pragma unroll
        for (int f = 0; f < NF; ++f) {
            size_t fb = (((size_t)ks * NF + f) * 64 + lane) * 8;
            bf16x8 bhi = *(const bf16x8*)(wpk + fb);
            bf16x8 blo = *(const bf16x8*)(wlo + fb);
            acc[f] = __builtin_amdgcn_mfma_f32_16x16x32_bf16(a, bhi, acc[f], 0, 0, 0);
            acc[f] = __builtin_amdgcn_mfma_f32_16x16x32_bf16(a, blo, acc[f], 0, 0, 0);
        }
    }

    int r0  = rowbase + (lane >> 4) * 4;
    int col = lane & 15;
#pragma unroll
    for (int f = 0; f < NF; ++f) {
#pragma unroll
        for (int i = 0; i < 4; ++i) {
            int r = r0 + i;
            if (r < n) Y[(size_t)r * ODIM + f * 16 + col] = f2bf(acc[f][i]);
        }
    }
}

// ---------------------------------------------------------------------------
// Gather1 (fp8 in, bf16 out), 2 EDGES PER WAVE-LOAD, HW fp8 decode:
//   v_cvt_pk_f32_fp8 converts 2 packed fp8 -> 2 f32 per instruction.
// ---------------------------------------------------------------------------
__global__ __launch_bounds__(256, 2)
void k_gather1(const unsigned char* __restrict__ xw, const int* __restrict__ rowptr,
               const int2* __restrict__ csr,
               const float* __restrict__ dinv, const float* __restrict__ bias,
               unsigned short* __restrict__ out, int n) {
    int wave = threadIdx.x >> 6;
    int lane = threadIdx.x & 63;
    int half = lane >> 5;
    int hl   = lane & 31;
    int i = blockIdx.x * 4 + wave;
    if (i >= n) return;

    float dv = dinv[i];
    float sl = dv * dv;
    int e0 = __builtin_amdgcn_readfirstlane(rowptr[i]);
    int e1 = __builtin_amdgcn_readfirstlane(rowptr[i + 1]);

    // self-loop (features 4hl..4hl+3, redundant across halves)
    unsigned int su = *(const unsigned int*)(xw + (size_t)i * 128 + hl * 4);
    vf2 sL = __builtin_amdgcn_cvt_pk_f32_fp8(su, false);
    vf2 sH = __builtin_amdgcn_cvt_pk_f32_fp8(su, true);
    float s0 = sL[0] * sl, s1 = sL[1] * sl, s2 = sH[0] * sl, s3 = sH[1] * sl;

    float ac0 = 0.f, ac1 = 0.f, ac2 = 0.f, ac3 = 0.f;
    int e = e0;
    for (; e + 8 <= e1; e += 8) {
        int2 q0 = csr[e + 0 + half];
        int2 q1 = csr[e + 2 + half];
        int2 q2 = csr[e + 4 + half];
        int2 q3 = csr[e + 6 + half];
        unsigned int u0 = *(const unsigned int*)(xw + (size_t)q0.x * 128 + hl * 4);
        unsigned int u1 = *(const unsigned int*)(xw + (size_t)q1.x * 128 + hl * 4);
        unsigned int u2 = *(const unsigned int*)(xw + (size_t)q2.x * 128 + hl * 4);
        unsigned int u3 = *(const unsigned int*)(xw + (size_t)q3.x * 128 + hl * 4);
        float c0 = __int_as_float(q0.y), c1 = __int_as_float(q1.y);
        float c2 = __int_as_float(q2.y), c3 = __int_as_float(q3.y);
        vf2 l0 = __builtin_amdgcn_cvt_pk_f32_fp8(u0, false);
        vf2 h0 = __builtin_amdgcn_cvt_pk_f32_fp8(u0, true);
        vf2 l1 = __builtin_amdgcn_cvt_pk_f32_fp8(u1, false);
        vf2 h1 = __builtin_amdgcn_cvt_pk_f32_fp8(u1, true);
        vf2 l2 = __builtin_amdgcn_cvt_pk_f32_fp8(u2, false);
        vf2 h2 = __builtin_amdgcn_cvt_pk_f32_fp8(u2, true);
        vf2 l3 = __builtin_amdgcn_cvt_pk_f32_fp8(u3, false);
        vf2 h3 = __builtin_amdgcn_cvt_pk_f32_fp8(u3, true);
        ac0 += c0 * l0[0]; ac1 += c0 * l0[1]; ac2 += c0 * h0[0]; ac3 += c0 * h0[1];
        ac0 += c1 * l1[0]; ac1 += c1 * l1[1]; ac2 += c1 * h1[0]; ac3 += c1 * h1[1];
        ac0 += c2 * l2[0]; ac1 += c2 * l2[1]; ac2 += c2 * h2[0]; ac3 += c2 * h2[1];
        ac0 += c3 * l3[0]; ac1 += c3 * l3[1]; ac2 += c3 * h3[0]; ac3 += c3 * h3[1];
    }
    for (; e + 2 <= e1; e += 2) {
        int2 q = csr[e + half];
        unsigned int u = *(const unsigned int*)(xw + (size_t)q.x * 128 + hl * 4);
        float c = __int_as_float(q.y);
        vf2 l = __builtin_amdgcn_cvt_pk_f32_fp8(u, false);
        vf2 h = __builtin_amdgcn_cvt_pk_f32_fp8(u, true);
        ac0 += c * l[0]; ac1 += c * l[1]; ac2 += c * h[0]; ac3 += c * h[1];
    }
    if (e < e1) {  // single edge: mask half 1
        int2 q = csr[e];
        unsigned int u = *(const unsigned int*)(xw + (size_t)q.x * 128 + hl * 4);
        float c = half ? 0.f : __int_as_float(q.y);
        vf2 l = __builtin_amdgcn_cvt_pk_f32_fp8(u, false);
        vf2 h = __builtin_amdgcn_cvt_pk_f32_fp8(u, true);
        ac0 += c * l[0]; ac1 += c * l[1]; ac2 += c * h[0]; ac3 += c * h[1];
    }
    // cross-half combine
    ac0 += __shfl_xor(ac0, 32);
    ac1 += __shfl_xor(ac1, 32);
    ac2 += __shfl_xor(ac2, 32);
    ac3 += __shfl_xor(ac3, 32);
    float4 bb = ((const float4*)bias)[hl];
    float f0 = fmaxf(ac0 + s0 + bb.x, 0.f);
    float f1 = fmaxf(ac1 + s1 + bb.y, 0.f);
    float f2 = fmaxf(ac2 + s2 + bb.z, 0.f);
    float f3 = fmaxf(ac3 + s3 + bb.w, 0.f);
    unsigned int w = half ? ((unsigned int)f2bf(f2) | ((unsigned int)f2bf(f3) << 16))
                          : ((unsigned int)f2bf(f0) | ((unsigned int)f2bf(f1) << 16));
    ((unsigned int*)(out + (size_t)i * 128))[2 * hl + half] = w;
}

// ---------------------------------------------------------------------------
// Gather2+pool (bf16 in), 2 EDGES PER WAVE-LOAD, barrier-free, NPW=4 nodes
// per wave sequential; pooled row in registers; per-graph-run atomics.
// ---------------------------------------------------------------------------
__global__ __launch_bounds__(256, 2)
void k_gather2_pool(const unsigned short* __restrict__ xw, const int* __restrict__ rowptr,
                    const int2* __restrict__ csr,
                    const float* __restrict__ dinv, const float* __restrict__ bias,
                    const int* __restrict__ batch, float* __restrict__ sums, int n) {
    constexpr int NPW = 4;
    int gwave = (blockIdx.x * blockDim.x + threadIdx.x) >> 6;
    int lane = threadIdx.x & 63;
    int half = lane >> 5;
    int hl   = lane & 31;
    int i0 = gwave * NPW;
    if (i0 >= n) return;
    int i1 = min(i0 + NPW, n);

    float2 bb = ((const float2*)bias)[hl];  // features 2hl, 2hl+1
    float p0 = 0.f, p1 = 0.f;
    int cg = __builtin_amdgcn_readfirstlane(batch[i0]);

    for (int i = i0; i < i1; ++i) {
        int g = __builtin_amdgcn_readfirstlane(batch[i]);
        if (g != cg) {
            float pv = half ? p1 : p0;
            atomicAdd(&sums[cg * 64 + 2 * hl + half], pv);
            p0 = 0.f; p1 = 0.f;
            cg = g;
        }
        float dv = dinv[i];
        float sl = dv * dv;
        int e0 = __builtin_amdgcn_readfirstlane(rowptr[i]);
        int e1 = __builtin_amdgcn_readfirstlane(rowptr[i + 1]);

        unsigned int su = ((const unsigned int*)(xw + (size_t)i * 64))[hl];
        float s0 = bf2f(su) * sl;
        float s1 = bf2f(su >> 16) * sl;
        float a0 = 0.f, a1 = 0.f;
        int e = e0;
        for (; e + 8 <= e1; e += 8) {
            int2 q0 = csr[e + 0 + half];
            int2 q1 = csr[e + 2 + half];
            int2 q2 = csr[e + 4 + half];
            int2 q3 = csr[e + 6 + half];
            unsigned int u0 = ((const unsigned int*)(xw + (size_t)q0.x * 64))[hl];
            unsigned int u1 = ((const unsigned int*)(xw + (size_t)q1.x * 64))[hl];
            unsigned int u2 = ((const unsigned int*)(xw + (size_t)q2.x * 64))[hl];
            unsigned int u3 = ((const unsigned int*)(xw + (size_t)q3.x * 64))[hl];
            float c0 = __int_as_float(q0.y), c1 = __int_as_float(q1.y);
            float c2 = __int_as_float(q2.y), c3 = __int_as_float(q3.y);
            a0 += c0 * bf2f(u0); a1 += c0 * bf2f(u0 >> 16);
            a0 += c1 * bf2f(u1); a1 += c1 * bf2f(u1 >> 16);
            a0 += c2 * bf2f(u2); a1 += c2 * bf2f(u2 >> 16);
            a0 += c3 * bf2f(u3); a1 += c3 * bf2f(u3 >> 16);
        }
        for (; e + 2 <= e1; e += 2) {
            int2 q = csr[e + half];
            unsigned int u = ((const unsigned int*)(xw + (size_t)q.x * 64))[hl];
            float c = __int_as_float(q.y);
            a0 += c * bf2f(u); a1 += c * bf2f(u >> 16);
        }
        if (e < e1) {  // single edge: mask half 1
            int2 q = csr[e];
            unsigned int u = ((const unsigned int*)(xw + (size_t)q.x * 64))[hl];
            float c = half ? 0.f : __int_as_float(q.y);
            a0 += c * bf2f(u); a1 += c * bf2f(u >> 16);
        }
        a0 += __shfl_xor(a0, 32);
        a1 += __shfl_xor(a1, 32);
        p0 += fmaxf(a0 + s0 + bb.x, 0.f);
        p1 += fmaxf(a1 + s1 + bb.y, 0.f);
    }
    float pv = half ? p1 : p0;
    atomicAdd(&sums[cg * 64 + 2 * hl + half], pv);
}

// out[g] = dot(sums[g]/cnt, Wfc) + bfc ; cnt via binary search on sorted batch
__global__ void k_head(const float* __restrict__ sums, const int* __restrict__ batch,
                       const float* __restrict__ Wfc, const float* __restrict__ bfc,
                       float* __restrict__ out, int n) {
    int g = blockIdx.x;
    int f = threadIdx.x;  // 64 threads = 1 wave
    int lo0 = 0, hi0 = n;
    while (lo0 < hi0) { int m = (lo0 + hi0) >> 1; if (batch[m] < g) lo0 = m + 1; else hi0 = m; }
    int lo1 = lo0, hi1 = n;
    while (lo1 < hi1) { int m = (lo1 + hi1) >> 1; if (batch[m] < g + 1) lo1 = m + 1; else hi1 = m; }
    float cnt = (float)(lo1 - lo0);
    float v = sums[g * 64 + f] * Wfc[f];
#pragma unroll
    for (int o = 32; o > 0; o >>= 1) v += __shfl_down(v, o);
    if (f == 0) out[g] = v / fmaxf(cnt, 1.0f) + bfc[0];
}

extern "C" void kernel_launch(void* const* d_in, const int* in_sizes, int n_in,
                              void* d_out, int out_size, void* d_ws, size_t ws_size,
                              hipStream_t stream) {
    const float* x    = (const float*)d_in[0];
    const int*   ei   = (const int*)d_in[1];
    const float* ew   = (const float*)d_in[2];
    const int*   bat  = (const int*)d_in[3];
    const float* W1   = (const float*)d_in[4];
    const float* b1   = (const float*)d_in[5];
    const float* W2   = (const float*)d_in[6];
    const float* b2   = (const float*)d_in[7];
    const float* Wfc  = (const float*)d_in[8];
    const float* bfc  = (const float*)d_in[9];
    float*       out  = (float*)d_out;

    const int N = in_sizes[0] / 256;
    const int E = in_sizes[2];
    const int G = out_size;

    const int* src = ei;
    const int* dst = ei + E;

    const int NB_SCAN = (N + SC_CHUNK - 1) / SC_CHUNK;

    // workspace layout (8B-aligned chunks)
    const int Npad = (N + 4) & ~3;
    unsigned long long* pk     = (unsigned long long*)d_ws;          // N u64
    float*              dinv   = (float*)(pk + Npad);                // N
    int*                count  = (int*)(dinv + Npad);                // N
    int*                rowptr = count + Npad;                       // N+1
    int*                bsum   = rowptr + Npad;                      // NB_SCAN
    int*                slot   = bsum + ((NB_SCAN + 4) & ~3);        // E
    int2*               csr    = (int2*)(slot + ((E + 4) & ~3));    // E int2
    unsigned short*     wpk1   = (unsigned short*)(csr + E);        // 2*256*128
    unsigned short*     wpk2   = wpk1 + 2 * 256 * 128;               // 2*128*64
    float*              sums   = (float*)(wpk2 + 2 * 128 * 64);     // G*64
    unsigned char*      bufA   = (unsigned char*)(sums + ((G * 64 + 4) & ~3)); // N*128 B: xw1 fp8 / xw2 bf16
    unsigned short*     bufH1  = (unsigned short*)(bufA + (size_t)N * 128);    // N*128 bf16: h1

    const int B = 256;

    // 1) packed degree + count (+ per-edge slot); finish also zeroes sums
    k_init_pk<<<ceil_div_ll(N, B), B, 0, stream>>>(pk, N);
    k_deg_count<<<ceil_div_ll((E + 3) / 4, B), B, 0, stream>>>(dst, ew, pk, slot, E);
    k_finish<<<ceil_div_ll(N, B), B, 0, stream>>>(pk, dinv, count, sums, G * 64, N);

    // 2) CSR build: parallel scan + atomic-free fill
    k_scan_a<<<NB_SCAN, SC_T, 0, stream>>>(count, bsum, N);
    k_scan_b<<<1, 64, 0, stream>>>(bsum, NB_SCAN);
    k_scan_c<<<NB_SCAN, SC_T, 0, stream>>>(count, rowptr, bsum, N);
    k_csr_fill<<<ceil_div_ll(E, B), B, 0, stream>>>(src, dst, ew, dinv, rowptr,
                                                    slot, csr, E);

    // W pre-pack
    k_wpack<256, 128><<<(8 * 8 * 64 + B - 1) / B, B, 0, stream>>>(W1, wpk1);
    k_wpack<128, 64><<<(4 * 4 * 64 + B - 1) / B, B, 0, stream>>>(W2, wpk2);

    // 3) layer 1: xw1(fp8) = x @ W1 ; h1(bf16) = relu(gather + b1)
    k_gemm_mfma<256, 128><<<ceil_div_ll(N, 64), 256, 0, stream>>>(x, wpk1, bufA, N);
    k_gather1<<<ceil_div_ll(N, 4), 256, 0, stream>>>(
        bufA, rowptr, csr, dinv, b1, bufH1, N);

    // 4) layer 2: xw2(bf16) = h1(bf16) @ W2 ; gather fused with mean-pool
    k_gemm_mfma_bfA<128, 64><<<ceil_div_ll(N, 64), 256, 0, stream>>>(
        bufH1, wpk2, (unsigned short*)bufA, N);
    {
        int waves = ceil_div_ll(N, 4);           // one wave per 4 nodes
        int blocks = ceil_div_ll(waves, 4);      // 4 waves per block
        k_gather2_pool<<<blocks, 256, 0, stream>>>(
            (const unsigned short*)bufA, rowptr, csr, dinv, b2, bat, sums, N);
    }

    // 5) head
    k_head<<<G, 64, 0, stream>>>(sums, bat, Wfc, bfc, out, N);
}

// Round 17
// 350.524 us; speedup vs baseline: 1.0864x; 1.0083x over previous
//
#include <hip/hip_runtime.h>
#include <hip/hip_bf16.h>
#include <hip/hip_fp16.h>
#include <hip/hip_fp8.h>

// ---------------------------------------------------------------------------
// RewardGNN: 2-layer GCN (256->128->64) + mean-pool + linear head.
// Round 17: revert gather2_pool to r14's full-wave barrier-free form (fastest
//   measured: 87us; r16 half-wave packing was -5us worse). Keep r16 gather1
//   (half-wave + HW v_cvt_pk_f32_fp8). deg_count: 8 edges/thread (2x atomic
//   MLP). xw1 fp8; h1 bf16; one-u64-atomic CSR; split-precision MFMA GEMMs.
// ---------------------------------------------------------------------------

static inline int ceil_div_ll(long long a, int b) { return (int)((a + b - 1) / b); }

typedef __attribute__((ext_vector_type(8))) short bf16x8;
typedef __attribute__((ext_vector_type(4))) float f32x4;
typedef __attribute__((ext_vector_type(2))) float vf2;

#define FIX_SCALE 33554432.0f   // 2^25

__device__ inline unsigned short f2bf(float f) {
    __hip_bfloat16 h = __float2bfloat16(f);  // round-to-nearest-even
    return *reinterpret_cast<unsigned short*>(&h);
}
__device__ inline float bf2f(unsigned int u) {
    return __uint_as_float((u & 0xffffu) << 16);
}
__device__ inline unsigned char f32_to_fp8(float f) {
    return __hip_cvt_float_to_fp8(f, __HIP_SATFINITE, __HIP_E4M3);
}

// pk[i] = count<<32 | deg_fixed ; init deg=1.0 (self-loop), count=0
__global__ void k_init_pk(unsigned long long* __restrict__ pk, int n) {
    int i = blockIdx.x * blockDim.x + threadIdx.x;
    if (i < n) pk[i] = (unsigned long long)(1u << 25);
}

// 8 edges per thread: 8 independent u64 atomics in flight (latency-bound)
__global__ void k_deg_count(const int* __restrict__ dst, const float* __restrict__ ew,
                            unsigned long long* __restrict__ pk, int* __restrict__ slot, int E) {
    int t = blockIdx.x * blockDim.x + threadIdx.x;
    int e = t * 8;
    if (e + 8 <= E) {
        int4   da = *(const int4*)(dst + e);
        int4   db = *(const int4*)(dst + e + 4);
        float4 wa = *(const float4*)(ew + e);
        float4 wb = *(const float4*)(ew + e + 4);
        unsigned long long o0 = atomicAdd(&pk[da.x],
            (1ull << 32) | (unsigned long long)__float2uint_rn(wa.x * FIX_SCALE));
        unsigned long long o1 = atomicAdd(&pk[da.y],
            (1ull << 32) | (unsigned long long)__float2uint_rn(wa.y * FIX_SCALE));
        unsigned long long o2 = atomicAdd(&pk[da.z],
            (1ull << 32) | (unsigned long long)__float2uint_rn(wa.z * FIX_SCALE));
        unsigned long long o3 = atomicAdd(&pk[da.w],
            (1ull << 32) | (unsigned long long)__float2uint_rn(wa.w * FIX_SCALE));
        unsigned long long o4 = atomicAdd(&pk[db.x],
            (1ull << 32) | (unsigned long long)__float2uint_rn(wb.x * FIX_SCALE));
        unsigned long long o5 = atomicAdd(&pk[db.y],
            (1ull << 32) | (unsigned long long)__float2uint_rn(wb.y * FIX_SCALE));
        unsigned long long o6 = atomicAdd(&pk[db.z],
            (1ull << 32) | (unsigned long long)__float2uint_rn(wb.z * FIX_SCALE));
        unsigned long long o7 = atomicAdd(&pk[db.w],
            (1ull << 32) | (unsigned long long)__float2uint_rn(wb.w * FIX_SCALE));
        *(int4*)(slot + e)     = make_int4((int)(o0 >> 32), (int)(o1 >> 32),
                                           (int)(o2 >> 32), (int)(o3 >> 32));
        *(int4*)(slot + e + 4) = make_int4((int)(o4 >> 32), (int)(o5 >> 32),
                                           (int)(o6 >> 32), (int)(o7 >> 32));
    } else if (e < E) {
        for (int k = e; k < E; ++k) {
            unsigned int fx = __float2uint_rn(ew[k] * FIX_SCALE);
            unsigned long long old =
                atomicAdd(&pk[dst[k]], (1ull << 32) | (unsigned long long)fx);
            slot[k] = (int)(old >> 32);
        }
    }
}

// dinv[i] = rsqrt(deg), count[i] = in-count ; also zeroes sums (pool accum)
__global__ void k_finish(const unsigned long long* __restrict__ pk, float* __restrict__ dinv,
                         int* __restrict__ count, float* __restrict__ sums, int nsums, int n) {
    int i = blockIdx.x * blockDim.x + threadIdx.x;
    if (i < n) {
        unsigned long long v = pk[i];
        float deg = (float)(unsigned int)(v & 0xffffffffull) * (1.0f / FIX_SCALE);
        dinv[i] = (deg > 0.f) ? rsqrtf(deg) : 0.f;
        count[i] = (int)(v >> 32);
    }
    if (i < nsums) sums[i] = 0.0f;
}

// ------------------------- 3-phase parallel scan ---------------------------
constexpr int SC_T = 256;
constexpr int SC_PER = 16;
constexpr int SC_CHUNK = SC_T * SC_PER;

__global__ void k_scan_a(const int* __restrict__ count, int* __restrict__ bsum, int n) {
    __shared__ int lds[SC_T];
    int b = blockIdx.x, t = threadIdx.x;
    int base = b * SC_CHUNK + t * SC_PER;
    int s = 0;
#pragma unroll
    for (int k = 0; k < SC_PER; ++k) {
        int idx = base + k;
        if (idx < n) s += count[idx];
    }
    lds[t] = s;
    __syncthreads();
    for (int off = 128; off > 0; off >>= 1) {
        if (t < off) lds[t] += lds[t + off];
        __syncthreads();
    }
    if (t == 0) bsum[b] = lds[0];
}

__global__ void k_scan_b(int* __restrict__ bsum, int nb) {
    if (threadIdx.x == 0) {
        int run = 0;
        for (int i = 0; i < nb; ++i) { int c = bsum[i]; bsum[i] = run; run += c; }
    }
}

__global__ void k_scan_c(const int* __restrict__ count, int* __restrict__ rowptr,
                         const int* __restrict__ bsum, int n) {
    __shared__ int lds[SC_T];
    int b = blockIdx.x, t = threadIdx.x;
    int base = b * SC_CHUNK + t * SC_PER;
    int v[SC_PER];
    int s = 0;
#pragma unroll
    for (int k = 0; k < SC_PER; ++k) {
        int idx = base + k;
        v[k] = (idx < n) ? count[idx] : 0;
        s += v[k];
    }
    lds[t] = s;
    for (int off = 1; off < SC_T; off <<= 1) {
        __syncthreads();
        int tmp = (t >= off) ? lds[t - off] : 0;
        __syncthreads();
        lds[t] += tmp;
    }
    __syncthreads();
    int run = bsum[b] + lds[t] - s;
#pragma unroll
    for (int k = 0; k < SC_PER; ++k) {
        int idx = base + k;
        if (idx < n) {
            rowptr[idx] = run;
            run += v[k];
            if (idx == n - 1) rowptr[n] = run;
        }
    }
}

// Fill CSR without atomics: pos = rowptr[dst] + slot[e]; one int2 store.
__global__ void k_csr_fill(const int* __restrict__ src, const int* __restrict__ dst,
                           const float* __restrict__ ew, const float* __restrict__ dinv,
                           const int* __restrict__ rowptr, const int* __restrict__ slot,
                           int2* __restrict__ csr, int E) {
    int e = blockIdx.x * blockDim.x + threadIdx.x;
    if (e < E) {
        int s = src[e], d = dst[e];
        int pos = rowptr[d] + slot[e];
        float coef = dinv[s] * ew[e] * dinv[d];
        csr[pos] = make_int2(s, __float_as_int(coef));
    }
}

// ---------------------------------------------------------------------------
// W pre-pack into MFMA B-fragment layout (hi/lo bf16).
// ---------------------------------------------------------------------------
template <int KDIM, int ODIM>
__global__ void k_wpack(const float* __restrict__ W, unsigned short* __restrict__ wpk) {
    constexpr int NKS = KDIM / 32, NF = ODIM / 16;
    int t = blockIdx.x * blockDim.x + threadIdx.x;
    if (t >= NKS * NF * 64) return;
    int lane = t & 63;
    int nf   = (t >> 6) % NF;
    int ks   = t / (64 * NF);
    int col  = nf * 16 + (lane & 15);
    int kb   = ks * 32 + (lane >> 4) * 8;
    bf16x8 hi, lo;
#pragma unroll
    for (int i = 0; i < 8; ++i) {
        float w = W[(size_t)(kb + i) * ODIM + col];
        unsigned short h = f2bf(w);
        hi[i] = (short)h;
        lo[i] = (short)f2bf(w - bf2f(h));
    }
    size_t base = (size_t)t * 8;
    *(bf16x8*)(wpk + base) = hi;
    *(bf16x8*)(wpk + (size_t)KDIM * ODIM + base) = lo;
}

// ---------------------------------------------------------------------------
// GEMM1: f32 A, split-precision (3 mfma), FP8 e4m3 out.
// ---------------------------------------------------------------------------
template <int KDIM, int ODIM>
__global__ void k_gemm_mfma(const float* __restrict__ X,
                            const unsigned short* __restrict__ wpk,
                            unsigned char* __restrict__ Y, int n) {
    constexpr int NKS = KDIM / 32, NF = ODIM / 16;
    int wid  = threadIdx.x >> 6;
    int lane = threadIdx.x & 63;
    int rowbase = blockIdx.x * 64 + wid * 16;
    int arow = rowbase + (lane & 15);
    int kb0  = (lane >> 4) * 8;
    const unsigned short* wlo = wpk + (size_t)KDIM * ODIM;
    bool aok = (arow < n);
    const float* xr = X + (size_t)arow * KDIM + kb0;

    f32x4 acc[NF];
#pragma unroll
    for (int f = 0; f < NF; ++f) acc[f] = (f32x4){0.f, 0.f, 0.f, 0.f};

#pragma unroll
    for (int ks = 0; ks < NKS; ++ks) {
        f32x4 a0 = (f32x4){0.f, 0.f, 0.f, 0.f};
        f32x4 a1 = (f32x4){0.f, 0.f, 0.f, 0.f};
        if (aok) {
            a0 = *(const f32x4*)(xr + ks * 32);
            a1 = *(const f32x4*)(xr + ks * 32 + 4);
        }
        bf16x8 ahi, alo;
#pragma unroll
        for (int i = 0; i < 4; ++i) {
            unsigned short h0 = f2bf(a0[i]);
            ahi[i]     = (short)h0;
            alo[i]     = (short)f2bf(a0[i] - bf2f(h0));
            unsigned short h1 = f2bf(a1[i]);
            ahi[i + 4] = (short)h1;
            alo[i + 4] = (short)f2bf(a1[i] - bf2f(h1));
        }
#pragma unroll
        for (int f = 0; f < NF; ++f) {
            size_t fb = (((size_t)ks * NF + f) * 64 + lane) * 8;
            bf16x8 bhi = *(const bf16x8*)(wpk + fb);
            bf16x8 blo = *(const bf16x8*)(wlo + fb);
            acc[f] = __builtin_amdgcn_mfma_f32_16x16x32_bf16(ahi, bhi, acc[f], 0, 0, 0);
            acc[f] = __builtin_amdgcn_mfma_f32_16x16x32_bf16(alo, bhi, acc[f], 0, 0, 0);
            acc[f] = __builtin_amdgcn_mfma_f32_16x16x32_bf16(ahi, blo, acc[f], 0, 0, 0);
        }
    }

    int r0  = rowbase + (lane >> 4) * 4;
    int col = lane & 15;
#pragma unroll
    for (int f = 0; f < NF; ++f) {
#pragma unroll
        for (int i = 0; i < 4; ++i) {
            int r = r0 + i;
            if (r < n) Y[(size_t)r * ODIM + f * 16 + col] = f32_to_fp8(acc[f][i]);
        }
    }
}

// ---------------------------------------------------------------------------
// GEMM2: bf16 A (h1 stored bf16 -> exact fragment, no split), B hi/lo (2 mfma).
// ---------------------------------------------------------------------------
template <int KDIM, int ODIM>
__global__ void k_gemm_mfma_bfA(const unsigned short* __restrict__ X,
                                const unsigned short* __restrict__ wpk,
                                unsigned short* __restrict__ Y, int n) {
    constexpr int NKS = KDIM / 32, NF = ODIM / 16;
    int wid  = threadIdx.x >> 6;
    int lane = threadIdx.x & 63;
    int rowbase = blockIdx.x * 64 + wid * 16;
    int arow = rowbase + (lane & 15);
    int kb0  = (lane >> 4) * 8;
    const unsigned short* wlo = wpk + (size_t)KDIM * ODIM;
    bool aok = (arow < n);
    const unsigned short* xr = X + (size_t)arow * KDIM + kb0;

    f32x4 acc[NF];
#pragma unroll
    for (int f = 0; f < NF; ++f) acc[f] = (f32x4){0.f, 0.f, 0.f, 0.f};

#pragma unroll
    for (int ks = 0; ks < NKS; ++ks) {
        bf16x8 a = (bf16x8){0, 0, 0, 0, 0, 0, 0, 0};
        if (aok) a = *(const bf16x8*)(xr + ks * 32);
#pragma unroll
        for (int f = 0; f < NF; ++f) {
            size_t fb = (((size_t)ks * NF + f) * 64 + lane) * 8;
            bf16x8 bhi = *(const bf16x8*)(wpk + fb);
            bf16x8 blo = *(const bf16x8*)(wlo + fb);
            acc[f] = __builtin_amdgcn_mfma_f32_16x16x32_bf16(a, bhi, acc[f], 0, 0, 0);
            acc[f] = __builtin_amdgcn_mfma_f32_16x16x32_bf16(a, blo, acc[f], 0, 0, 0);
        }
    }

    int r0  = rowbase + (lane >> 4) * 4;
    int col = lane & 15;
#pragma unroll
    for (int f = 0; f < NF; ++f) {
#pragma unroll
        for (int i = 0; i < 4; ++i) {
            int r = r0 + i;
            if (r < n) Y[(size_t)r * ODIM + f * 16 + col] = f2bf(acc[f][i]);
        }
    }
}

// ---------------------------------------------------------------------------
// Gather1 (fp8 in, bf16 out), 2 EDGES PER WAVE-LOAD, HW fp8 decode.
// ---------------------------------------------------------------------------
__global__ __launch_bounds__(256, 2)
void k_gather1(const unsigned char* __restrict__ xw, const int* __restrict__ rowptr,
               const int2* __restrict__ csr,
               const float* __restrict__ dinv, const float* __restrict__ bias,
               unsigned short* __restrict__ out, int n) {
    int wave = threadIdx.x >> 6;
    int lane = threadIdx.x & 63;
    int half = lane >> 5;
    int hl   = lane & 31;
    int i = blockIdx.x * 4 + wave;
    if (i >= n) return;

    float dv = dinv[i];
    float sl = dv * dv;
    int e0 = __builtin_amdgcn_readfirstlane(rowptr[i]);
    int e1 = __builtin_amdgcn_readfirstlane(rowptr[i + 1]);

    unsigned int su = *(const unsigned int*)(xw + (size_t)i * 128 + hl * 4);
    vf2 sL = __builtin_amdgcn_cvt_pk_f32_fp8(su, false);
    vf2 sH = __builtin_amdgcn_cvt_pk_f32_fp8(su, true);
    float s0 = sL[0] * sl, s1 = sL[1] * sl, s2 = sH[0] * sl, s3 = sH[1] * sl;

    float ac0 = 0.f, ac1 = 0.f, ac2 = 0.f, ac3 = 0.f;
    int e = e0;
    for (; e + 8 <= e1; e += 8) {
        int2 q0 = csr[e + 0 + half];
        int2 q1 = csr[e + 2 + half];
        int2 q2 = csr[e + 4 + half];
        int2 q3 = csr[e + 6 + half];
        unsigned int u0 = *(const unsigned int*)(xw + (size_t)q0.x * 128 + hl * 4);
        unsigned int u1 = *(const unsigned int*)(xw + (size_t)q1.x * 128 + hl * 4);
        unsigned int u2 = *(const unsigned int*)(xw + (size_t)q2.x * 128 + hl * 4);
        unsigned int u3 = *(const unsigned int*)(xw + (size_t)q3.x * 128 + hl * 4);
        float c0 = __int_as_float(q0.y), c1 = __int_as_float(q1.y);
        float c2 = __int_as_float(q2.y), c3 = __int_as_float(q3.y);
        vf2 l0 = __builtin_amdgcn_cvt_pk_f32_fp8(u0, false);
        vf2 h0 = __builtin_amdgcn_cvt_pk_f32_fp8(u0, true);
        vf2 l1 = __builtin_amdgcn_cvt_pk_f32_fp8(u1, false);
        vf2 h1 = __builtin_amdgcn_cvt_pk_f32_fp8(u1, true);
        vf2 l2 = __builtin_amdgcn_cvt_pk_f32_fp8(u2, false);
        vf2 h2 = __builtin_amdgcn_cvt_pk_f32_fp8(u2, true);
        vf2 l3 = __builtin_amdgcn_cvt_pk_f32_fp8(u3, false);
        vf2 h3 = __builtin_amdgcn_cvt_pk_f32_fp8(u3, true);
        ac0 += c0 * l0[0]; ac1 += c0 * l0[1]; ac2 += c0 * h0[0]; ac3 += c0 * h0[1];
        ac0 += c1 * l1[0]; ac1 += c1 * l1[1]; ac2 += c1 * h1[0]; ac3 += c1 * h1[1];
        ac0 += c2 * l2[0]; ac1 += c2 * l2[1]; ac2 += c2 * h2[0]; ac3 += c2 * h2[1];
        ac0 += c3 * l3[0]; ac1 += c3 * l3[1]; ac2 += c3 * h3[0]; ac3 += c3 * h3[1];
    }
    for (; e + 2 <= e1; e += 2) {
        int2 q = csr[e + half];
        unsigned int u = *(const unsigned int*)(xw + (size_t)q.x * 128 + hl * 4);
        float c = __int_as_float(q.y);
        vf2 l = __builtin_amdgcn_cvt_pk_f32_fp8(u, false);
        vf2 h = __builtin_amdgcn_cvt_pk_f32_fp8(u, true);
        ac0 += c * l[0]; ac1 += c * l[1]; ac2 += c * h[0]; ac3 += c * h[1];
    }
    if (e < e1) {  // single edge: mask half 1
        int2 q = csr[e];
        unsigned int u = *(const unsigned int*)(xw + (size_t)q.x * 128 + hl * 4);
        float c = half ? 0.f : __int_as_float(q.y);
        vf2 l = __builtin_amdgcn_cvt_pk_f32_fp8(u, false);
        vf2 h = __builtin_amdgcn_cvt_pk_f32_fp8(u, true);
        ac0 += c * l[0]; ac1 += c * l[1]; ac2 += c * h[0]; ac3 += c * h[1];
    }
    ac0 += __shfl_xor(ac0, 32);
    ac1 += __shfl_xor(ac1, 32);
    ac2 += __shfl_xor(ac2, 32);
    ac3 += __shfl_xor(ac3, 32);
    float4 bb = ((const float4*)bias)[hl];
    float f0 = fmaxf(ac0 + s0 + bb.x, 0.f);
    float f1 = fmaxf(ac1 + s1 + bb.y, 0.f);
    float f2 = fmaxf(ac2 + s2 + bb.z, 0.f);
    float f3 = fmaxf(ac3 + s3 + bb.w, 0.f);
    unsigned int w = half ? ((unsigned int)f2bf(f2) | ((unsigned int)f2bf(f3) << 16))
                          : ((unsigned int)f2bf(f0) | ((unsigned int)f2bf(f1) << 16));
    ((unsigned int*)(out + (size_t)i * 128))[2 * hl + half] = w;
}

// ---------------------------------------------------------------------------
// Gather2+pool (bf16 in), FULL-WAVE (r14 form: fastest measured), barrier-free,
// NPW=4 nodes per wave sequential; pooled row in registers; per-run atomics.
// ---------------------------------------------------------------------------
__global__ __launch_bounds__(256, 2)
void k_gather2_pool(const unsigned short* __restrict__ xw, const int* __restrict__ rowptr,
                    const int2* __restrict__ csr,
                    const float* __restrict__ dinv, const float* __restrict__ bias,
                    const int* __restrict__ batch, float* __restrict__ sums, int n) {
    constexpr int NPW = 4;
    int gwave = (blockIdx.x * blockDim.x + threadIdx.x) >> 6;
    int lane = threadIdx.x & 63;
    int i0 = gwave * NPW;
    if (i0 >= n) return;
    int i1 = min(i0 + NPW, n);

    float bb = bias[lane];
    float acc = 0.f;
    int cg = __builtin_amdgcn_readfirstlane(batch[i0]);

    for (int i = i0; i < i1; ++i) {
        int g = __builtin_amdgcn_readfirstlane(batch[i]);
        if (g != cg) {
            atomicAdd(&sums[cg * 64 + lane], acc);
            acc = 0.f;
            cg = g;
        }
        float dv = dinv[i];
        float sl = dv * dv;
        int e0 = __builtin_amdgcn_readfirstlane(rowptr[i]);
        int e1 = __builtin_amdgcn_readfirstlane(rowptr[i + 1]);

        float a0 = bf2f(xw[(size_t)i * 64 + lane]) * sl;
        float a1 = 0.f, a2 = 0.f, a3 = 0.f;
        int e = e0;
        for (; e + 8 <= e1; e += 8) {
            int2 p0 = csr[e + 0], p1 = csr[e + 1], p2 = csr[e + 2], p3 = csr[e + 3];
            int2 p4 = csr[e + 4], p5 = csr[e + 5], p6 = csr[e + 6], p7 = csr[e + 7];
            float v0 = bf2f(xw[(size_t)p0.x * 64 + lane]);
            float v1 = bf2f(xw[(size_t)p1.x * 64 + lane]);
            float v2 = bf2f(xw[(size_t)p2.x * 64 + lane]);
            float v3 = bf2f(xw[(size_t)p3.x * 64 + lane]);
            float v4 = bf2f(xw[(size_t)p4.x * 64 + lane]);
            float v5 = bf2f(xw[(size_t)p5.x * 64 + lane]);
            float v6 = bf2f(xw[(size_t)p6.x * 64 + lane]);
            float v7 = bf2f(xw[(size_t)p7.x * 64 + lane]);
            a0 += __int_as_float(p0.y) * v0; a1 += __int_as_float(p1.y) * v1;
            a2 += __int_as_float(p2.y) * v2; a3 += __int_as_float(p3.y) * v3;
            a0 += __int_as_float(p4.y) * v4; a1 += __int_as_float(p5.y) * v5;
            a2 += __int_as_float(p6.y) * v6; a3 += __int_as_float(p7.y) * v7;
        }
        for (; e + 2 <= e1; e += 2) {
            int2 p0 = csr[e + 0], p1 = csr[e + 1];
            a0 += __int_as_float(p0.y) * bf2f(xw[(size_t)p0.x * 64 + lane]);
            a1 += __int_as_float(p1.y) * bf2f(xw[(size_t)p1.x * 64 + lane]);
        }
        if (e < e1) {
            int2 p0 = csr[e];
            a0 += __int_as_float(p0.y) * bf2f(xw[(size_t)p0.x * 64 + lane]);
        }
        acc += fmaxf((a0 + a1) + (a2 + a3) + bb, 0.f);
    }
    atomicAdd(&sums[cg * 64 + lane], acc);
}

// out[g] = dot(sums[g]/cnt, Wfc) + bfc ; cnt via binary search on sorted batch
__global__ void k_head(const float* __restrict__ sums, const int* __restrict__ batch,
                       const float* __restrict__ Wfc, const float* __restrict__ bfc,
                       float* __restrict__ out, int n) {
    int g = blockIdx.x;
    int f = threadIdx.x;  // 64 threads = 1 wave
    int lo0 = 0, hi0 = n;
    while (lo0 < hi0) { int m = (lo0 + hi0) >> 1; if (batch[m] < g) lo0 = m + 1; else hi0 = m; }
    int lo1 = lo0, hi1 = n;
    while (lo1 < hi1) { int m = (lo1 + hi1) >> 1; if (batch[m] < g + 1) lo1 = m + 1; else hi1 = m; }
    float cnt = (float)(lo1 - lo0);
    float v = sums[g * 64 + f] * Wfc[f];
#pragma unroll
    for (int o = 32; o > 0; o >>= 1) v += __shfl_down(v, o);
    if (f == 0) out[g] = v / fmaxf(cnt, 1.0f) + bfc[0];
}

extern "C" void kernel_launch(void* const* d_in, const int* in_sizes, int n_in,
                              void* d_out, int out_size, void* d_ws, size_t ws_size,
                              hipStream_t stream) {
    const float* x    = (const float*)d_in[0];
    const int*   ei   = (const int*)d_in[1];
    const float* ew   = (const float*)d_in[2];
    const int*   bat  = (const int*)d_in[3];
    const float* W1   = (const float*)d_in[4];
    const float* b1   = (const float*)d_in[5];
    const float* W2   = (const float*)d_in[6];
    const float* b2   = (const float*)d_in[7];
    const float* Wfc  = (const float*)d_in[8];
    const float* bfc  = (const float*)d_in[9];
    float*       out  = (float*)d_out;

    const int N = in_sizes[0] / 256;
    const int E = in_sizes[2];
    const int G = out_size;

    const int* src = ei;
    const int* dst = ei + E;

    const int NB_SCAN = (N + SC_CHUNK - 1) / SC_CHUNK;

    // workspace layout (8B-aligned chunks)
    const int Npad = (N + 4) & ~3;
    unsigned long long* pk     = (unsigned long long*)d_ws;          // N u64
    float*              dinv   = (float*)(pk + Npad);                // N
    int*                count  = (int*)(dinv + Npad);                // N
    int*                rowptr = count + Npad;                       // N+1
    int*                bsum   = rowptr + Npad;                      // NB_SCAN
    int*                slot   = bsum + ((NB_SCAN + 4) & ~3);        // E
    int2*               csr    = (int2*)(slot + ((E + 4) & ~3));    // E int2
    unsigned short*     wpk1   = (unsigned short*)(csr + E);        // 2*256*128
    unsigned short*     wpk2   = wpk1 + 2 * 256 * 128;               // 2*128*64
    float*              sums   = (float*)(wpk2 + 2 * 128 * 64);     // G*64
    unsigned char*      bufA   = (unsigned char*)(sums + ((G * 64 + 4) & ~3)); // N*128 B: xw1 fp8 / xw2 bf16
    unsigned short*     bufH1  = (unsigned short*)(bufA + (size_t)N * 128);    // N*128 bf16: h1

    const int B = 256;

    // 1) packed degree + count (+ per-edge slot); finish also zeroes sums
    k_init_pk<<<ceil_div_ll(N, B), B, 0, stream>>>(pk, N);
    k_deg_count<<<ceil_div_ll((E + 7) / 8, B), B, 0, stream>>>(dst, ew, pk, slot, E);
    k_finish<<<ceil_div_ll(N, B), B, 0, stream>>>(pk, dinv, count, sums, G * 64, N);

    // 2) CSR build: parallel scan + atomic-free fill
    k_scan_a<<<NB_SCAN, SC_T, 0, stream>>>(count, bsum, N);
    k_scan_b<<<1, 64, 0, stream>>>(bsum, NB_SCAN);
    k_scan_c<<<NB_SCAN, SC_T, 0, stream>>>(count, rowptr, bsum, N);
    k_csr_fill<<<ceil_div_ll(E, B), B, 0, stream>>>(src, dst, ew, dinv, rowptr,
                                                    slot, csr, E);

    // W pre-pack
    k_wpack<256, 128><<<(8 * 8 * 64 + B - 1) / B, B, 0, stream>>>(W1, wpk1);
    k_wpack<128, 64><<<(4 * 4 * 64 + B - 1) / B, B, 0, stream>>>(W2, wpk2);

    // 3) layer 1: xw1(fp8) = x @ W1 ; h1(bf16) = relu(gather + b1)
    k_gemm_mfma<256, 128><<<ceil_div_ll(N, 64), 256, 0, stream>>>(x, wpk1, bufA, N);
    k_gather1<<<ceil_div_ll(N, 4), 256, 0, stream>>>(
        bufA, rowptr, csr, dinv, b1, bufH1, N);

    // 4) layer 2: xw2(bf16) = h1(bf16) @ W2 ; gather fused with mean-pool
    k_gemm_mfma_bfA<128, 64><<<ceil_div_ll(N, 64), 256, 0, stream>>>(
        bufH1, wpk2, (unsigned short*)bufA, N);
    {
        int waves = ceil_div_ll(N, 4);           // one wave per 4 nodes
        int blocks = ceil_div_ll(waves, 4);      // 4 waves per block
        k_gather2_pool<<<blocks, 256, 0, stream>>>(
            (const unsigned short*)bufA, rowptr, csr, dinv, b2, bat, sums, N);
    }

    // 5) head
    k_head<<<G, 64, 0, stream>>>(sums, bat, Wfc, bfc, out, N);
}